// Round 4
// baseline (1025.131 us; speedup 1.0000x reference)
//
#include <hip/hip_runtime.h>
#include <stdint.h>

#define NN   16384
#define HID  256
#define LDSK 264            // padded LDS row stride in f16 elems (16B-aligned)
#define FLTMAX 3.402823466e38f

typedef __attribute__((ext_vector_type(8))) _Float16 f16x8;
typedef __attribute__((ext_vector_type(4))) _Float16 f16x4;
typedef __attribute__((ext_vector_type(4))) float f32x4;

// ---- fp32 -> fp16 converter ----
__global__ __launch_bounds__(256) void cvt_kernel(const float* __restrict__ in,
                                                  _Float16* __restrict__ out){
  int t = blockIdx.x * 256 + threadIdx.x;
  float4 v = ((const float4*)in)[t];
  f16x4 h; h.x = (_Float16)v.x; h.y = (_Float16)v.y; h.z = (_Float16)v.z; h.w = (_Float16)v.w;
  ((f16x4*)out)[t] = h;
}

// ---- row sum-of-squares, bit-replicating numpy fp32 pairwise summation ----
// numpy: m = xs*xs (fp32 elementwise); np.sum pairwise for n=256: two 128-halves,
// each: 8 stride-8 accumulators, combine ((r0+r1)+(r2+r3))+((r4+r5)+(r6+r7));
// total = left + right. Contraction OFF so the multiply rounds separately.
__global__ __launch_bounds__(256) void sumsq_np_kernel(const float* __restrict__ x,
                                                       float* __restrict__ sqf){
  #pragma clang fp contract(off)
  int row = blockIdx.x * 256 + threadIdx.x;
  const float* p = x + (size_t)row * HID;
  float half[2];
  #pragma unroll
  for (int h = 0; h < 2; ++h){
    float r[8];
    #pragma unroll
    for (int j = 0; j < 8; ++j){ float v = p[h*128 + j]; float m = v*v; r[j] = m; }
    for (int i = 8; i < 128; i += 8){
      #pragma unroll
      for (int j = 0; j < 8; ++j){ float v = p[h*128 + i + j]; float m = v*v; r[j] = r[j] + m; }
    }
    half[h] = ((r[0]+r[1]) + (r[2]+r[3])) + ((r[4]+r[5]) + (r[6]+r[7]));
  }
  sqf[row] = half[0] + half[1];
}

// stage 64x256 f16 tile into LDS with padded stride
__device__ __forceinline__ void load_tile64(unsigned short* dst, const unsigned short* src, int tid){
  const uint4* s = (const uint4*)src;
  #pragma unroll
  for (int r = 0; r < 8; ++r){
    int fl  = tid + (r << 8);
    int row = fl >> 5;
    int c   = fl & 31;
    *(uint4*)&dst[row*LDSK + (c << 3)] = s[fl];
  }
}

// running top-4 (smallest) insert, strict <
#define UPD(dv, jv) do { float d_=(dv); if (d_ < bd3) { int j_=(jv); \
  if      (d_ < bd0){bd3=bd2;bi3=bi2;bd2=bd1;bi2=bi1;bd1=bd0;bi1=bi0;bd0=d_;bi0=j_;} \
  else if (d_ < bd1){bd3=bd2;bi3=bi2;bd2=bd1;bi2=bi1;bd1=d_;bi1=j_;} \
  else if (d_ < bd2){bd3=bd2;bi3=bi2;bd2=d_;bi2=j_;} \
  else              {bd3=d_;bi3=j_;} } } while(0)

// fp16 MFMA Gram; emit 16 candidate neighbor indices per row (4 per column-quarter).
// fp16 metric noise sigma~0.01 << exact 4/5 gap ~1.8 -> recall is safe; exact
// membership decided by the np-replicating rescore below.
__global__ __launch_bounds__(256) void knn_kernel(const _Float16* __restrict__ xh,
                                                  const float* __restrict__ sqf,
                                                  int* __restrict__ cand16){
  __shared__ unsigned short Xj[64 * LDSK];
  __shared__ float D[64 * 68];
  __shared__ float sqj[64];

  int tid = threadIdx.x;
  int i0  = blockIdx.x * 64;
  int wave = tid >> 6, lane = tid & 63, quad = lane >> 4, lcol = lane & 15;

  f16x8 a[8];
  const _Float16* arow = xh + (size_t)(i0 + wave*16 + lcol) * HID + quad*8;
  #pragma unroll
  for (int ks = 0; ks < 8; ++ks) a[ks] = *(const f16x8*)(arow + ks*32);

  float bd0=FLTMAX, bd1=FLTMAX, bd2=FLTMAX, bd3=FLTMAX;
  int   bi0=0, bi1=0, bi2=0, bi3=0;

  for (int jb = 0; jb < NN; jb += 64){
    __syncthreads();
    load_tile64(Xj, (const unsigned short*)(xh + (size_t)jb * HID), tid);
    if (tid < 64) sqj[tid] = sqf[jb + tid];
    __syncthreads();

    #pragma unroll
    for (int sub = 0; sub < 4; ++sub){
      f32x4 acc = {0.f, 0.f, 0.f, 0.f};
      #pragma unroll
      for (int ks = 0; ks < 8; ++ks){
        f16x8 b = *(const f16x8*)&Xj[(sub*16 + lcol)*LDSK + quad*8 + ks*32];
        acc = __builtin_amdgcn_mfma_f32_16x16x32_f16(a[ks], b, acc, 0, 0, 0);
      }
      int   gj = jb + sub*16 + lcol;                   // C/D: col = lane&15
      float sj = sqj[sub*16 + lcol];
      #pragma unroll
      for (int reg = 0; reg < 4; ++reg){               // C/D: row = quad*4 + reg
        int gi = i0 + wave*16 + quad*4 + reg;
        float v = (gi == gj) ? FLTMAX : fmaf(-2.f, acc[reg], sj);
        D[(wave*16 + quad*4 + reg)*68 + sub*16 + lcol] = v;
      }
    }
    __syncthreads();

    const float4* pr = (const float4*)&D[(wave*16 + lcol)*68 + quad*16];
    #pragma unroll
    for (int q = 0; q < 4; ++q){
      float4 v = pr[q];
      int j0 = jb + quad*16 + q*4;
      UPD(v.x, j0); UPD(v.y, j0+1); UPD(v.z, j0+2); UPD(v.w, j0+3);
    }
  }

  int gi = i0 + wave*16 + lcol;
  int base = (gi << 4) + quad*4;
  cand16[base+0] = bi0; cand16[base+1] = bi1;
  cand16[base+2] = bi2; cand16[base+3] = bi3;
}

// Rescore the 16 candidates replicating the np reference's fp32 pipeline
// op-for-op:
//   dot  = sequential-in-k fp32 FMA chain  (OpenBLAS sgemm microkernel: one
//          accumulator per c_ij, rank-1 updates k=0..255 in natural order)
//   d2   = fl32( fl32(sq_i + sq_j) - 2*dot )   (2*dot exact)
// Rank by (d2, index) lex (stable top_k tie-break). One block of 64 thr / row.
__global__ __launch_bounds__(64) void rescore_kernel(const float* __restrict__ x,
                                                     const float* __restrict__ sqf,
                                                     const int* __restrict__ cand16,
                                                     int* __restrict__ idx_out,
                                                     int* __restrict__ Bdeg){
  #pragma clang fp contract(off)
  __shared__ float Xi[256];
  __shared__ float Xc[16][260];   // 260: float4-aligned rows, 2-way-bank-free chain reads
  __shared__ float dc[16];
  __shared__ int   jc[16];
  int i = blockIdx.x;
  int t = threadIdx.x;            // 0..63
  ((float4*)Xi)[t] = ((const float4*)(x + (size_t)i * HID))[t];
  if (t < 16) jc[t] = cand16[(i << 4) + t];
  __syncthreads();
  for (int r = 0; r < 16; ++r){
    int j = jc[r];
    ((float4*)&Xc[r][0])[t] = ((const float4*)(x + (size_t)j * HID))[t];
  }
  __syncthreads();
  if (t < 16){
    float acc = 0.f;
    for (int k = 0; k < 256; ++k) acc = fmaf(Xi[k], Xc[t][k], acc);
    float t1 = sqf[i] + sqf[jc[t]];
    dc[t] = t1 - 2.0f * acc;
  }
  __syncthreads();
  if (t == 0){
    unsigned taken = 0;
    #pragma unroll
    for (int k = 0; k < 4; ++k){
      float bd = FLTMAX; int bj = 0x7fffffff, bs = -1;
      for (int s = 0; s < 16; ++s){
        if (taken & (1u << s)) continue;
        float d = dc[s]; int j = jc[s];
        if (d < bd || (d == bd && j < bj)){ bd = d; bj = j; bs = s; }
      }
      taken |= 1u << bs;
      idx_out[i*4 + k] = bj;
      atomicAdd(&Bdeg[bj], 1);
    }
  }
}

// out[i][o] = sum_k A[i][k] * W[o][k]   (A: Mx256 f16, W staged f16, out f16)
__global__ __launch_bounds__(256) void gemm_xw(const _Float16* __restrict__ A,
                                               const _Float16* __restrict__ W,
                                               _Float16* __restrict__ out){
  __shared__ unsigned short Ws[64 * LDSK];
  int tid = threadIdx.x;
  int i0 = (blockIdx.x >> 2) * 64;
  int o0 = (blockIdx.x & 3)  * 64;
  int wave = tid >> 6, lane = tid & 63, quad = lane >> 4, lcol = lane & 15;
  load_tile64(Ws, (const unsigned short*)(W + (size_t)o0 * HID), tid);
  f16x8 a[8];
  const _Float16* arow = A + (size_t)(i0 + wave*16 + lcol) * HID + quad*8;
  #pragma unroll
  for (int ks = 0; ks < 8; ++ks) a[ks] = *(const f16x8*)(arow + ks*32);
  __syncthreads();
  #pragma unroll
  for (int sub = 0; sub < 4; ++sub){
    f32x4 acc = {0.f, 0.f, 0.f, 0.f};
    #pragma unroll
    for (int ks = 0; ks < 8; ++ks){
      f16x8 b = *(const f16x8*)&Ws[(sub*16 + lcol)*LDSK + quad*8 + ks*32];
      acc = __builtin_amdgcn_mfma_f32_16x16x32_f16(a[ks], b, acc, 0, 0, 0);
    }
    #pragma unroll
    for (int reg = 0; reg < 4; ++reg)
      out[(size_t)(i0 + wave*16 + quad*4 + reg)*HID + o0 + sub*16 + lcol] = (_Float16)acc[reg];
  }
}

__global__ __launch_bounds__(256) void prefix_kernel(const int* __restrict__ Bdeg,
                                                     int* __restrict__ off,
                                                     int* __restrict__ cursor){
  __shared__ int psum[256];
  __shared__ int excl[256];
  int t = threadIdx.x;
  int base = t * 64;
  int s = 0;
  for (int k = 0; k < 64; ++k) s += Bdeg[base + k];
  psum[t] = s;
  __syncthreads();
  if (t == 0){ int a = 0; for (int k = 0; k < 256; ++k){ excl[k] = a; a += psum[k]; } }
  __syncthreads();
  int a = excl[t];
  for (int k = 0; k < 64; ++k){ int dv = Bdeg[base + k]; off[base+k] = a; cursor[base+k] = a; a += dv; }
}

__global__ __launch_bounds__(256) void fill_kernel(const int* __restrict__ idx,
                                                   int* __restrict__ cursor,
                                                   int* __restrict__ rev){
  int i = blockIdx.x * 256 + threadIdx.x;
  #pragma unroll
  for (int t = 0; t < 4; ++t){
    int e = idx[i*4 + t];
    int p = atomicAdd(&cursor[e], 1);
    rev[p] = i;
  }
}

// E[e] = mean over contributing nodes of xt[node]  (gather via reverse CSR)
__global__ __launch_bounds__(256) void efeat_kernel(const _Float16* __restrict__ xt,
                                                    const int* __restrict__ off,
                                                    const int* __restrict__ deg,
                                                    const int* __restrict__ rev,
                                                    _Float16* __restrict__ E){
  int e = blockIdx.x, c = threadIdx.x;
  int o = off[e], d = deg[e];
  float s = 0.f;
  for (int k = 0; k < d; ++k) s += (float)xt[(size_t)rev[o + k]*HID + c];
  E[(size_t)e*HID + c] = (_Float16)((d > 0) ? s / (float)d : 0.f);
}

__global__ __launch_bounds__(256) void fin1_kernel(const _Float16* __restrict__ E,
                                                   const int* __restrict__ idx,
                                                   const float* __restrict__ b1,
                                                   const float* __restrict__ pa,
                                                   _Float16* __restrict__ h1){
  int i = blockIdx.x, c = threadIdx.x;
  const int* ip = idx + i*4;
  float s = (float)E[(size_t)ip[0]*HID + c] + (float)E[(size_t)ip[1]*HID + c]
          + (float)E[(size_t)ip[2]*HID + c] + (float)E[(size_t)ip[3]*HID + c];
  float acc = 0.25f * s + b1[c];
  float a = pa[0];
  acc = (acc >= 0.f) ? acc : a * acc;
  h1[(size_t)i*HID + c] = (_Float16)acc;
}

__global__ __launch_bounds__(256) void fin2_kernel(const _Float16* __restrict__ E,
                                                   const int* __restrict__ idx,
                                                   const float* __restrict__ b2,
                                                   const float* __restrict__ x,
                                                   const float* __restrict__ pa,
                                                   float* __restrict__ out){
  int i = blockIdx.x, c = threadIdx.x;
  const int* ip = idx + i*4;
  float s = (float)E[(size_t)ip[0]*HID + c] + (float)E[(size_t)ip[1]*HID + c]
          + (float)E[(size_t)ip[2]*HID + c] + (float)E[(size_t)ip[3]*HID + c];
  float acc = 0.25f * s + b2[c] + x[(size_t)i*HID + c];
  float a = pa[0];
  acc = (acc >= 0.f) ? acc : a * acc;
  out[(size_t)i*HID + c] = acc;
}

extern "C" void kernel_launch(void* const* d_in, const int* in_sizes, int n_in,
                              void* d_out, int out_size, void* d_ws, size_t ws_size,
                              hipStream_t stream){
  (void)in_sizes; (void)n_in; (void)out_size; (void)ws_size;
  const float* x  = (const float*)d_in[0];
  // d_in[1] = edge_index (int32), unused by the math
  const float* W1 = (const float*)d_in[2];
  const float* b1 = (const float*)d_in[3];
  const float* W2 = (const float*)d_in[4];
  const float* b2 = (const float*)d_in[5];
  const float* pa = (const float*)d_in[6];
  float* out = (float*)d_out;

  char* ws = (char*)d_ws;
  float*  sqf    = (float*) (ws + 0);                        //  64 KB
  int*    idx    = (int*)   (ws + 65536);                    // 256 KB
  int*    Bdeg   = (int*)   (ws + 327680);                   //  64 KB
  int*    offE   = (int*)   (ws + 393216);                   //  64 KB
  int*    cursor = (int*)   (ws + 458752);                   //  64 KB
  int*    rev    = (int*)   (ws + 524288);                   // 256 KB
  int*    cand16 = (int*)   (ws + (size_t)(1<<20));          //   1 MB
  _Float16* xh   = (_Float16*)(ws + (size_t)(2<<20));        //   8 MB
  _Float16* W1h  = (_Float16*)(ws + (size_t)(10<<20));       // 128 KB
  _Float16* W2h  = (_Float16*)(ws + (size_t)(10<<20) + 131072);
  _Float16* xt   = (_Float16*)(ws + (size_t)(10<<20) + 262144);            // 8 MB
  _Float16* E    = (_Float16*)(ws + (size_t)(18<<20) + 262144);            // 8 MB
  _Float16* h1   = (_Float16*)(ws + (size_t)(26<<20) + 262144);            // 8 MB

  hipMemsetAsync(Bdeg, 0, NN*sizeof(int), stream);
  cvt_kernel    <<<(NN*HID)/1024, 256, 0, stream>>>(x,  xh);
  cvt_kernel    <<<(HID*HID)/1024, 256, 0, stream>>>(W1, W1h);
  cvt_kernel    <<<(HID*HID)/1024, 256, 0, stream>>>(W2, W2h);
  sumsq_np_kernel<<<NN/256, 256, 0, stream>>>(x, sqf);
  knn_kernel    <<<NN/64,  256, 0, stream>>>(xh, sqf, cand16);
  rescore_kernel<<<NN,      64, 0, stream>>>(x, sqf, cand16, idx, Bdeg);
  prefix_kernel <<<1,      256, 0, stream>>>(Bdeg, offE, cursor);
  fill_kernel   <<<NN/256, 256, 0, stream>>>(idx, cursor, rev);

  gemm_xw       <<<(NN/64)*4, 256, 0, stream>>>(xh, W1h, xt);
  efeat_kernel  <<<NN,        256, 0, stream>>>(xt, offE, Bdeg, rev, E);
  fin1_kernel   <<<NN,        256, 0, stream>>>(E, idx, b1, pa, h1);

  gemm_xw       <<<(NN/64)*4, 256, 0, stream>>>(h1, W2h, xt);
  efeat_kernel  <<<NN,        256, 0, stream>>>(xt, offE, Bdeg, rev, E);
  fin2_kernel   <<<NN,        256, 0, stream>>>(E, idx, b2, x, pa, out);
}